// Round 15
// baseline (504.738 us; speedup 1.0000x reference)
//
#include <hip/hip_runtime.h>
#include <math.h>

#define NB 8
#define PP 2048
#define DD 64
#define EPSF 1e-3f
#define RCPE 1000.0f
#define TMAX 10
#define THRESHF 0.1f
#define NEG_INF (-1e30f)
#define QSCALE 32767.5f                 // cost in [0,2] -> u16
#define S_DEQ  (1.0f / 32767.5f)
#define KR 512                          // row candidate cap
#define KC 512                          // col candidate cap (4 segs x 128)
#define TSEL 0.15f                      // selection margin (PROVEN: 0.12 fails, r6)
// NOTE (r8): cooperative grid.sync costs ~115 us/sync on gfx950. Do not retry.
// NOTE (r12): folding combine into 16-block weights => 65us latency-bound
// collapse. Wide gathers need wide grids. Keep combine separate.
// NOTE (r15): select row path = bitmask+scan (no ballots); col path = direct
// strided reads, wave=512-row seg, lane=col (no LDS transpose, no barriers).

typedef __attribute__((ext_vector_type(8))) short bf16x8;
typedef __attribute__((ext_vector_type(4))) float f32x4;

__device__ __forceinline__ float waveAllMax(float v) {
#pragma unroll
    for (int m = 1; m < 64; m <<= 1) v = fmaxf(v, __shfl_xor(v, m, 64));
    return v;
}
__device__ __forceinline__ float waveAllMin(float v) {
#pragma unroll
    for (int m = 1; m < 64; m <<= 1) v = fminf(v, __shfl_xor(v, m, 64));
    return v;
}
__device__ __forceinline__ float waveAllSum(float v) {
#pragma unroll
    for (int m = 1; m < 64; m <<= 1) v += __shfl_xor(v, m, 64);
    return v;
}
__device__ __forceinline__ short f2bf(float x) {   // round-to-nearest-even bf16
    unsigned b = __float_as_uint(x);
    return (short)((b + 0x7FFFu + ((b >> 16) & 1u)) >> 16);
}
__device__ __forceinline__ float bf2f(short h) {
    return __uint_as_float(((unsigned)(unsigned short)h) << 16);
}

// ---- L2 normalize + bf16 hi/lo split (+ init of u/v/conv/out) --------------
__global__ void norm_kernel(const float* __restrict__ a, const float* __restrict__ b,
                            short* __restrict__ ahi, short* __restrict__ alo,
                            short* __restrict__ bhi, short* __restrict__ blo,
                            float* __restrict__ u, float* __restrict__ v,
                            int* __restrict__ conv, float* __restrict__ out) {
    int gt = blockIdx.x * 256 + threadIdx.x;
    if (gt < NB * PP) { u[gt] = 0.0f; v[gt] = 0.0f; }
    if (gt == 0) *conv = 0;
    if (gt < NB) out[gt] = 0.0f;
    int wave = gt >> 6;
    int lane = threadIdx.x & 63;
    const float* src; short* dhi; short* dlo; int row;
    if (wave < NB * PP) { src = a; dhi = ahi; dlo = alo; row = wave; }
    else                { src = b; dhi = bhi; dlo = blo; row = wave - NB * PP; }
    float x = src[(size_t)row * DD + lane];
    float ss = waveAllSum(x * x);
    float r = 1.0f / fmaxf(sqrtf(ss), 1e-12f);
    float xn = x * r;
    short h = f2bf(xn);
    dhi[(size_t)row * DD + lane] = h;
    dlo[(size_t)row * DD + lane] = f2bf(xn - bf2f(h));
}

// ---- cost GEMM via bf16-split MFMA, pre-split fragments direct from global -
__global__ __launch_bounds__(256) void cost_kernel(const short* __restrict__ ahi,
        const short* __restrict__ alo, const short* __restrict__ bhi,
        const short* __restrict__ blo, unsigned short* __restrict__ C16,
        float* __restrict__ rpart, float* __restrict__ cpart,
        unsigned* __restrict__ rminp, unsigned* __restrict__ cminp) {
    __shared__ float    rsum2[256];
    __shared__ unsigned rmin2[256];
    __shared__ float    csum2[256];
    __shared__ unsigned cmin2[256];
    int b  = blockIdx.z;
    int i0 = blockIdx.y * 128;
    int j0 = blockIdx.x * 128;
    int t = threadIdx.x, w = t >> 6, lane = t & 63;
    int wi = w >> 1, wj = w & 1;
    int quad = lane >> 4, li = lane & 15;
    size_t Aoff = ((size_t)b * PP + i0 + wi * 64) * DD;
    size_t Boff = ((size_t)b * PP + j0 + wj * 64) * DD;
    f32x4 acc[4][4] = {};
#pragma unroll
    for (int kc = 0; kc < 2; ++kc) {
        int k0 = kc * 32 + quad * 8;
        bf16x8 fah[4], fal[4];
#pragma unroll
        for (int mt = 0; mt < 4; ++mt) {
            size_t o = Aoff + (size_t)(mt * 16 + li) * DD + k0;
            fah[mt] = *(const bf16x8*)(ahi + o);
            fal[mt] = *(const bf16x8*)(alo + o);
        }
#pragma unroll
        for (int nt = 0; nt < 4; ++nt) {
            size_t o = Boff + (size_t)(li * 4 + nt) * DD + k0;
            bf16x8 fbh = *(const bf16x8*)(bhi + o);
            bf16x8 fbl = *(const bf16x8*)(blo + o);
#pragma unroll
            for (int mt = 0; mt < 4; ++mt) {
                acc[mt][nt] = __builtin_amdgcn_mfma_f32_16x16x32_bf16(
                        fah[mt], fbh, acc[mt][nt], 0, 0, 0);
                acc[mt][nt] = __builtin_amdgcn_mfma_f32_16x16x32_bf16(
                        fah[mt], fbl, acc[mt][nt], 0, 0, 0);
                acc[mt][nt] = __builtin_amdgcn_mfma_f32_16x16x32_bf16(
                        fal[mt], fbh, acc[mt][nt], 0, 0, 0);
            }
        }
    }
    // ---- epilogue: quant store + row/col sum & min partials ----------------
    float csum[4] = {0.f, 0.f, 0.f, 0.f};
    unsigned cmin[4] = {0xFFFFFFFFu, 0xFFFFFFFFu, 0xFFFFFFFFu, 0xFFFFFFFFu};
#pragma unroll
    for (int mt = 0; mt < 4; ++mt) {
#pragma unroll
        for (int r = 0; r < 4; ++r) {
            int irow = wi * 64 + mt * 16 + quad * 4 + r;   // local row 0..127
            float rs = 0.0f; unsigned rm = 0xFFFFFFFFu;
            unsigned short qv[4];
#pragma unroll
            for (int nt = 0; nt < 4; ++nt) {
                int jl = wj * 64 + li * 4 + nt;            // local col 0..127
                float dot = acc[mt][nt][r];
                float cost = fminf(fmaxf(1.0f - dot, 0.0f), 2.0f);
                unsigned q = __float2uint_rn(cost * QSCALE);
                qv[nt] = (unsigned short)q;
                rs += dot;
                rm = min(rm, (q << 16) | (unsigned)(j0 + jl));
                csum[nt] += dot;
                cmin[nt] = min(cmin[nt], (q << 16) | (unsigned)(i0 + irow));
            }
            *(ushort4*)&C16[((size_t)b * PP + i0 + irow) * PP + j0 + wj * 64 + li * 4] =
                make_ushort4(qv[0], qv[1], qv[2], qv[3]);
#pragma unroll
            for (int m = 1; m < 16; m <<= 1) {
                rs += __shfl_xor(rs, m, 64);
                rm = min(rm, (unsigned)__shfl_xor((int)rm, m, 64));
            }
            if (li == 0) { rsum2[wj * 128 + irow] = rs; rmin2[wj * 128 + irow] = rm; }
        }
    }
#pragma unroll
    for (int nt = 0; nt < 4; ++nt) {
        float cv = csum[nt]; unsigned cmv = cmin[nt];
#pragma unroll
        for (int m = 16; m < 64; m <<= 1) {
            cv += __shfl_xor(cv, m, 64);
            cmv = min(cmv, (unsigned)__shfl_xor((int)cmv, m, 64));
        }
        if (quad == 0) {
            int jl = wj * 64 + li * 4 + nt;
            csum2[wi * 128 + jl] = cv; cmin2[wi * 128 + jl] = cmv;
        }
    }
    __syncthreads();
    if (t < 128) {
        rpart[(size_t)blockIdx.x * (NB * PP) + b * PP + i0 + t] = rsum2[t] + rsum2[128 + t];
        rminp[(size_t)blockIdx.x * (NB * PP) + b * PP + i0 + t] = min(rmin2[t], rmin2[128 + t]);
        cpart[(size_t)blockIdx.y * (NB * PP) + b * PP + j0 + t] = csum2[t] + csum2[128 + t];
        cminp[(size_t)blockIdx.y * (NB * PP) + b * PP + j0 + t] = min(cmin2[t], cmin2[128 + t]);
    }
}

// ---- combine partials (wide grid: 64 blocks) -------------------------------
__global__ void combine_kernel(const float* __restrict__ rpart, const float* __restrict__ cpart,
                               const unsigned* __restrict__ rminp, const unsigned* __restrict__ cminp,
                               float* __restrict__ rowS, float* __restrict__ colS,
                               unsigned* __restrict__ rowminp, unsigned* __restrict__ colminp) {
    int idx = blockIdx.x * 256 + threadIdx.x;
    float rs = 0.0f, csf = 0.0f;
    unsigned rm = 0xFFFFFFFFu, cm = 0xFFFFFFFFu;
#pragma unroll
    for (int k = 0; k < 16; ++k) {
        rs  += rpart[(size_t)k * (NB * PP) + idx];
        csf += cpart[(size_t)k * (NB * PP) + idx];
        rm = min(rm, rminp[(size_t)k * (NB * PP) + idx]);
        cm = min(cm, cminp[(size_t)k * (NB * PP) + idx]);
    }
    rowS[idx] = rs; colS[idx] = csf;
    rowminp[idx] = rm; colminp[idx] = cm;
}

// ---- weights + thresholds --------------------------------------------------
__device__ __forceinline__ float blockReduceSum256(float v, float* sh) {
    v = waveAllSum(v);
    int lane = threadIdx.x & 63, w = threadIdx.x >> 6;
    if (lane == 0) sh[w] = v;
    __syncthreads();
    float r = sh[0] + sh[1] + sh[2] + sh[3];
    __syncthreads();
    return r;
}

__global__ void weights_kernel(const float* __restrict__ rowS, const float* __restrict__ colS,
                               const unsigned* __restrict__ rowminp, const unsigned* __restrict__ colminp,
                               float* __restrict__ elm, float* __restrict__ eln,
                               float* __restrict__ rowminf, float* __restrict__ colminf,
                               float* __restrict__ cthresh) {
    __shared__ float sh[4];
    int b = blockIdx.x & 7;
    bool isB = blockIdx.x >= 8;
    const float* src = (isB ? colS : rowS) + b * PP;
    float* dst = (isB ? eln : elm) + b * PP;
    int tid = threadIdx.x;
    float x[8];
    float sabs = 0.0f;
#pragma unroll
    for (int q = 0; q < 8; ++q) {
        x[q] = src[tid + q * 256] * (1.0f / (float)PP);
        sabs += fabsf(x[q]);
    }
    sabs = blockReduceSum256(sabs, sh);
    float inv1 = 1.0f / fmaxf(sabs, 1e-12f);
    float spos = 0.0f;
#pragma unroll
    for (int q = 0; q < 8; ++q) {
        x[q] = fmaxf(x[q] * inv1, 0.0f);
        spos += x[q];
    }
    spos = blockReduceSum256(spos, sh);
    float inv2 = 1.0f / fmaxf(spos, 1e-12f);
#pragma unroll
    for (int q = 0; q < 8; ++q)
        dst[tid + q * 256] = EPSF * logf(x[q] * inv2 + 1e-8f);
    if (isB) {
#pragma unroll
        for (int q = 0; q < 8; ++q) {
            int idx = b * PP + tid + q * 256;
            unsigned pc = colminp[idx];
            unsigned arg = pc & 0xffffu;
            unsigned pr = rowminp[b * PP + arg];
            float cmf = (float)(pc >> 16) * S_DEQ;
            colminf[idx] = cmf;
            cthresh[idx] = cmf - (float)(pr >> 16) * S_DEQ + TSEL;
        }
    } else {
#pragma unroll
        for (int q = 0; q < 8; ++q) {
            int idx = b * PP + tid + q * 256;
            rowminf[idx] = (float)(rowminp[idx] >> 16) * S_DEQ;
        }
    }
}

// ---- fused candidate selection: blocks [0,4096) rows, [4096,4352) col slabs
__global__ __launch_bounds__(256) void select_kernel(const unsigned short* __restrict__ C16,
        const float* __restrict__ colminf, const float* __restrict__ rowminf,
        const float* __restrict__ cthresh,
        unsigned* __restrict__ rlist, int* __restrict__ rcnt,
        unsigned* __restrict__ clist, int* __restrict__ scnt) {
    int w = threadIdx.x >> 6, lane = threadIdx.x & 63;
    if (blockIdx.x < 4096) {
        // ---- row path: bitmask + prefix-scan compaction (no ballots) -------
        int row = blockIdx.x * 4 + w;
        int b = row >> 11;
        const uint4* cp = (const uint4*)(C16 + (size_t)row * PP);
        uint4 q4[4];
#pragma unroll
        for (int g = 0; g < 4; ++g) q4[g] = cp[g * 64 + lane];
        const float* cmb = colminf + b * PP;
        float rpmin = 1e30f;
#pragma unroll
        for (int g = 0; g < 4; ++g) {
            int jb = g * 512 + lane * 8;
            float4 cm0 = *(const float4*)(cmb + jb);
            float4 cm1 = *(const float4*)(cmb + jb + 4);
            float cm[8] = {cm0.x, cm0.y, cm0.z, cm0.w, cm1.x, cm1.y, cm1.z, cm1.w};
            unsigned qq[4] = {q4[g].x, q4[g].y, q4[g].z, q4[g].w};
#pragma unroll
            for (int h = 0; h < 4; ++h) {
                float c0 = (float)(qq[h] & 0xffffu) * S_DEQ;
                float c1 = (float)(qq[h] >> 16) * S_DEQ;
                rpmin = fminf(rpmin, fminf(c0 - cm[h * 2], c1 - cm[h * 2 + 1]));
            }
        }
        float rth = waveAllMin(rpmin) + TSEL;
        // build per-lane candidate mask
        unsigned msk = 0;
#pragma unroll
        for (int g = 0; g < 4; ++g) {
            int jb = g * 512 + lane * 8;
            float4 cm0 = *(const float4*)(cmb + jb);
            float4 cm1 = *(const float4*)(cmb + jb + 4);
            float cm[8] = {cm0.x, cm0.y, cm0.z, cm0.w, cm1.x, cm1.y, cm1.z, cm1.w};
            unsigned qq[4] = {q4[g].x, q4[g].y, q4[g].z, q4[g].w};
#pragma unroll
            for (int e = 0; e < 8; ++e) {
                unsigned q = (qq[e >> 1] >> ((e & 1) * 16)) & 0xffffu;
                float cf = (float)q * S_DEQ;
                if ((cf - cm[e]) <= rth) msk |= 1u << (g * 8 + e);
            }
        }
        int myc = __popc(msk);
        int inc = myc;                       // inclusive scan across lanes
#pragma unroll
        for (int m = 1; m < 64; m <<= 1) {
            int tv = __shfl_up(inc, m, 64);
            if (lane >= m) inc += tv;
        }
        int pos = inc - myc;                 // exclusive base
        unsigned* dst = rlist + (size_t)row * KR;
#pragma unroll
        for (int g = 0; g < 4; ++g) {
            unsigned qq[4] = {q4[g].x, q4[g].y, q4[g].z, q4[g].w};
#pragma unroll
            for (int e = 0; e < 8; ++e) {
                if (msk & (1u << (g * 8 + e))) {
                    unsigned q = (qq[e >> 1] >> ((e & 1) * 16)) & 0xffffu;
                    int j = g * 512 + lane * 8 + e;
                    if (pos < KR) dst[pos] = ((unsigned)j << 16) | q;
                    ++pos;
                }
            }
        }
        if (lane == 63) rcnt[row] = inc;     // lane63 inclusive == total
    } else {
        // ---- col path: wave = 512-row seg, lane = col; direct reads --------
        int bid = blockIdx.x - 4096;
        int b = bid >> 5;
        int j0 = (bid & 31) * 64;
        int col = j0 + lane;
        float ctj = cthresh[b * PP + col];
        const float* rmb = rowminf + b * PP + w * 512;
        const unsigned short* cp = C16 + ((size_t)b * PP + w * 512) * PP + col;
        unsigned* mylist = clist + (size_t)(b * PP + col) * KC + w * 128;
        int cnt = 0;
        for (int r = 0; r < 512; r += 8) {
            unsigned short cs[8];
#pragma unroll
            for (int k = 0; k < 8; ++k) cs[k] = cp[(size_t)(r + k) * PP];
#pragma unroll
            for (int k = 0; k < 8; ++k) {
                float cf = (float)cs[k] * S_DEQ;
                if (cf - rmb[r + k] <= ctj) {
                    if (cnt < 128) mylist[cnt] = ((unsigned)(w * 512 + r + k) << 16) | cs[k];
                    ++cnt;
                }
            }
        }
        scnt[(b * PP + col) * 4 + w] = min(cnt, 128);
    }
}

// ---- Sinkhorn u-update over row candidates (wave per row) ------------------
__global__ __launch_bounds__(256) void u_kernel(const unsigned* __restrict__ rlist,
        const int* __restrict__ rcnt, const float* __restrict__ v,
        const float* __restrict__ elm, float* __restrict__ u, float* __restrict__ du,
        const int* __restrict__ conv) {
    if (*conv) return;
    int w = threadIdx.x >> 6, lane = threadIdx.x & 63;
    int row = blockIdx.x * 4 + w;
    int b = row >> 11;
    int cnt = min(rcnt[row], KR);
    const unsigned* lst = rlist + (size_t)row * KR;
    const float* vb = v + (b << 11);
    float x[8];
    float m = NEG_INF;
#pragma unroll
    for (int s = 0; s < 8; ++s) {
        int e = lane + s * 64;
        x[s] = NEG_INF;
        if (e < cnt) {
            unsigned wd = lst[e];
            x[s] = vb[wd >> 16] - (float)(wd & 0xffffu) * S_DEQ;
        }
        m = fmaxf(m, x[s]);
    }
    m = waveAllMax(m);
    float s = 0.0f;
#pragma unroll
    for (int k = 0; k < 8; ++k) s += __expf((x[k] - m) * RCPE);
    s = waveAllSum(s);
    if (lane == 0) {
        float un = elm[row] - m - EPSF * logf(s);
        du[row] = fabsf(un - u[row]);
        u[row] = un;
    }
}

// ---- Sinkhorn v-update over col candidates (+ err/conv in block 0) ---------
__global__ __launch_bounds__(256) void v_kernel(const unsigned* __restrict__ clist,
        const int* __restrict__ scnt, const float* __restrict__ u,
        const float* __restrict__ eln, float* __restrict__ v,
        const float* __restrict__ du, int* __restrict__ conv) {
    if (*conv) return;
    int w = threadIdx.x >> 6, lane = threadIdx.x & 63;
    int jg = blockIdx.x * 4 + w;
    int b = jg >> 11;
    int4 sc = *(const int4*)&scnt[jg * 4];
    int cn[4] = {sc.x, sc.y, sc.z, sc.w};
    const unsigned* lst = clist + (size_t)jg * KC;
    const float* ub = u + (b << 11);
    float x[8];
    float m = NEG_INF;
#pragma unroll
    for (int s = 0; s < 8; ++s) {
        int e = lane + s * 64;
        int sg = e >> 7, k = e & 127;
        x[s] = NEG_INF;
        if (k < cn[sg]) {
            unsigned wd = lst[sg * 128 + k];
            x[s] = ub[wd >> 16] - (float)(wd & 0xffffu) * S_DEQ;
        }
        m = fmaxf(m, x[s]);
    }
    m = waveAllMax(m);
    float s = 0.0f;
#pragma unroll
    for (int k = 0; k < 8; ++k) s += __expf((x[k] - m) * RCPE);
    s = waveAllSum(s);
    if (lane == 0)
        v[jg] = eln[jg] - m - EPSF * logf(s);
    if (blockIdx.x == 0) {
        __shared__ float sh[4];
        int t = threadIdx.x;
        float sacc = 0.0f;
#pragma unroll
        for (int q = 0; q < 64; ++q) sacc += du[t + q * 256];
        sacc = waveAllSum(sacc);
        if (lane == 0) sh[w] = sacc;
        __syncthreads();
        if (t == 0) {
            float tot = sh[0] + sh[1] + sh[2] + sh[3];
            if (tot * (1.0f / (float)NB) < THRESHF) *conv = 1;
        }
    }
}

// ---- final: D[b] = sum over row candidates of exp((u+v-C)/eps)*C -----------
__global__ __launch_bounds__(256) void emd_kernel(const unsigned* __restrict__ rlist,
        const int* __restrict__ rcnt, const float* __restrict__ u,
        const float* __restrict__ v, float* __restrict__ out) {
    __shared__ float sh[4];
    int w = threadIdx.x >> 6, lane = threadIdx.x & 63;
    int row = blockIdx.x * 4 + w;
    int b = row >> 11;
    int cnt = min(rcnt[row], KR);
    const unsigned* lst = rlist + (size_t)row * KR;
    const float* vb = v + (b << 11);
    float ui = u[row];
    float s = 0.0f;
#pragma unroll
    for (int k = 0; k < 8; ++k) {
        int e = lane + k * 64;
        if (e < cnt) {
            unsigned wd = lst[e];
            float cf = (float)(wd & 0xffffu) * S_DEQ;
            s += __expf((ui + vb[wd >> 16] - cf) * RCPE) * cf;
        }
    }
    s = waveAllSum(s);
    if (lane == 0) sh[w] = s;
    __syncthreads();
    if (threadIdx.x == 0) atomicAdd(&out[b], sh[0] + sh[1] + sh[2] + sh[3]);
}

extern "C" void kernel_launch(void* const* d_in, const int* in_sizes, int n_in,
                              void* d_out, int out_size, void* d_ws, size_t ws_size,
                              hipStream_t stream) {
    const float* a = (const float*)d_in[0];
    const float* b = (const float*)d_in[1];
    float* out = (float*)d_out;

    const size_t MBs = 1024ull * 1024ull;
    char* ws = (char*)d_ws;
    unsigned short* C16 = (unsigned short*)ws;              // 64 MB
    short* ahi   = (short*)(ws + 64 * MBs);                 // 2 MB each
    short* alo   = (short*)(ws + 66 * MBs);
    short* bhi   = (short*)(ws + 68 * MBs);
    short* blo   = (short*)(ws + 70 * MBs);
    float* rpart = (float*)(ws + 72 * MBs);
    float* cpart = (float*)(ws + 73 * MBs);
    unsigned* rminp = (unsigned*)(ws + 74 * MBs);
    unsigned* cminp = (unsigned*)(ws + 75 * MBs);
    unsigned* rlist = (unsigned*)(ws + 64 * MBs);           // 32 MB, alias
    unsigned* clist = (unsigned*)(ws + 96 * MBs);           // 32 MB
    char* tail = ws + 128 * MBs;
    size_t off = 0;
    const size_t szV = (size_t)NB * PP * 4;                 // 64 KB
    int*   scnt    = (int*)(tail + off); off += (size_t)NB * PP * 4 * 4;
    float* rowS    = (float*)(tail + off); off += szV;
    float* colS    = (float*)(tail + off); off += szV;
    unsigned* rowminp = (unsigned*)(tail + off); off += szV;
    unsigned* colminp = (unsigned*)(tail + off); off += szV;
    float* rowminf = (float*)(tail + off); off += szV;
    float* colminf = (float*)(tail + off); off += szV;
    float* cthresh = (float*)(tail + off); off += szV;
    float* elm     = (float*)(tail + off); off += szV;
    float* eln     = (float*)(tail + off); off += szV;
    float* u       = (float*)(tail + off); off += szV;
    float* v       = (float*)(tail + off); off += szV;
    float* du      = (float*)(tail + off); off += szV;
    int*   rcnt    = (int*)(tail + off); off += szV;
    int*   conv    = (int*)(tail + off); off += 64;
    if (ws_size < 128 * MBs + off) return;

    norm_kernel<<<(2 * NB * PP) / 4, 256, 0, stream>>>(a, b, ahi, alo, bhi, blo,
            u, v, conv, out);
    cost_kernel<<<dim3(PP / 128, PP / 128, NB), 256, 0, stream>>>(
            ahi, alo, bhi, blo, C16, rpart, cpart, rminp, cminp);
    combine_kernel<<<64, 256, 0, stream>>>(rpart, cpart, rminp, cminp,
            rowS, colS, rowminp, colminp);
    weights_kernel<<<16, 256, 0, stream>>>(rowS, colS, rowminp, colminp,
            elm, eln, rowminf, colminf, cthresh);
    select_kernel<<<4096 + NB * 32, 256, 0, stream>>>(C16, colminf, rowminf,
            cthresh, rlist, rcnt, clist, scnt);
    for (int it = 0; it < TMAX; ++it) {
        u_kernel<<<NB * PP / 4, 256, 0, stream>>>(rlist, rcnt, v, elm, u, du, conv);
        v_kernel<<<NB * PP / 4, 256, 0, stream>>>(clist, scnt, u, eln, v, du, conv);
    }
    emd_kernel<<<NB * PP / 4, 256, 0, stream>>>(rlist, rcnt, u, v, out);
}

// Round 16
// 396.711 us; speedup vs baseline: 1.2723x; 1.2723x over previous
//
#include <hip/hip_runtime.h>
#include <math.h>

#define NB 8
#define PP 2048
#define DD 64
#define EPSF 1e-3f
#define RCPE 1000.0f
#define TMAX 10
#define THRESHF 0.1f
#define NEG_INF (-1e30f)
#define QSCALE 32767.5f                 // cost in [0,2] -> u16
#define S_DEQ  (1.0f / 32767.5f)
#define KR 512                          // row candidate cap
#define KC 512                          // col candidate cap (4 segs x 128)
#define TSEL 0.15f                      // selection margin (PROVEN: 0.12 fails, r6)
// NOTE (r8): cooperative grid.sync costs ~115 us/sync on gfx950. Do not retry.
// NOTE (r12): folding combine into 16-block weights => latency collapse.
// NOTE (r15): col select with 2B/lane strided loads => 2x regression.
//             Keep >=16B/lane coalesced reads on streaming paths.
// NOTE (r16): col select = r14 LDS-transpose path, split 4x by row-quarter
//             (1024 blocks, 8 chunks each, LDS-atomic append per col).

typedef __attribute__((ext_vector_type(8))) short bf16x8;
typedef __attribute__((ext_vector_type(4))) float f32x4;

__device__ __forceinline__ float waveAllMax(float v) {
#pragma unroll
    for (int m = 1; m < 64; m <<= 1) v = fmaxf(v, __shfl_xor(v, m, 64));
    return v;
}
__device__ __forceinline__ float waveAllMin(float v) {
#pragma unroll
    for (int m = 1; m < 64; m <<= 1) v = fminf(v, __shfl_xor(v, m, 64));
    return v;
}
__device__ __forceinline__ float waveAllSum(float v) {
#pragma unroll
    for (int m = 1; m < 64; m <<= 1) v += __shfl_xor(v, m, 64);
    return v;
}
__device__ __forceinline__ short f2bf(float x) {   // round-to-nearest-even bf16
    unsigned b = __float_as_uint(x);
    return (short)((b + 0x7FFFu + ((b >> 16) & 1u)) >> 16);
}
__device__ __forceinline__ float bf2f(short h) {
    return __uint_as_float(((unsigned)(unsigned short)h) << 16);
}

// ---- L2 normalize + bf16 hi/lo split (+ init of u/v/conv/out) --------------
__global__ void norm_kernel(const float* __restrict__ a, const float* __restrict__ b,
                            short* __restrict__ ahi, short* __restrict__ alo,
                            short* __restrict__ bhi, short* __restrict__ blo,
                            float* __restrict__ u, float* __restrict__ v,
                            int* __restrict__ conv, float* __restrict__ out) {
    int gt = blockIdx.x * 256 + threadIdx.x;
    if (gt < NB * PP) { u[gt] = 0.0f; v[gt] = 0.0f; }
    if (gt == 0) *conv = 0;
    if (gt < NB) out[gt] = 0.0f;
    int wave = gt >> 6;
    int lane = threadIdx.x & 63;
    const float* src; short* dhi; short* dlo; int row;
    if (wave < NB * PP) { src = a; dhi = ahi; dlo = alo; row = wave; }
    else                { src = b; dhi = bhi; dlo = blo; row = wave - NB * PP; }
    float x = src[(size_t)row * DD + lane];
    float ss = waveAllSum(x * x);
    float r = 1.0f / fmaxf(sqrtf(ss), 1e-12f);
    float xn = x * r;
    short h = f2bf(xn);
    dhi[(size_t)row * DD + lane] = h;
    dlo[(size_t)row * DD + lane] = f2bf(xn - bf2f(h));
}

// ---- cost GEMM via bf16-split MFMA, pre-split fragments direct from global -
__global__ __launch_bounds__(256) void cost_kernel(const short* __restrict__ ahi,
        const short* __restrict__ alo, const short* __restrict__ bhi,
        const short* __restrict__ blo, unsigned short* __restrict__ C16,
        float* __restrict__ rpart, float* __restrict__ cpart,
        unsigned* __restrict__ rminp, unsigned* __restrict__ cminp) {
    __shared__ float    rsum2[256];
    __shared__ unsigned rmin2[256];
    __shared__ float    csum2[256];
    __shared__ unsigned cmin2[256];
    int b  = blockIdx.z;
    int i0 = blockIdx.y * 128;
    int j0 = blockIdx.x * 128;
    int t = threadIdx.x, w = t >> 6, lane = t & 63;
    int wi = w >> 1, wj = w & 1;
    int quad = lane >> 4, li = lane & 15;
    size_t Aoff = ((size_t)b * PP + i0 + wi * 64) * DD;
    size_t Boff = ((size_t)b * PP + j0 + wj * 64) * DD;
    f32x4 acc[4][4] = {};
#pragma unroll
    for (int kc = 0; kc < 2; ++kc) {
        int k0 = kc * 32 + quad * 8;
        bf16x8 fah[4], fal[4];
#pragma unroll
        for (int mt = 0; mt < 4; ++mt) {
            size_t o = Aoff + (size_t)(mt * 16 + li) * DD + k0;
            fah[mt] = *(const bf16x8*)(ahi + o);
            fal[mt] = *(const bf16x8*)(alo + o);
        }
#pragma unroll
        for (int nt = 0; nt < 4; ++nt) {
            size_t o = Boff + (size_t)(li * 4 + nt) * DD + k0;
            bf16x8 fbh = *(const bf16x8*)(bhi + o);
            bf16x8 fbl = *(const bf16x8*)(blo + o);
#pragma unroll
            for (int mt = 0; mt < 4; ++mt) {
                acc[mt][nt] = __builtin_amdgcn_mfma_f32_16x16x32_bf16(
                        fah[mt], fbh, acc[mt][nt], 0, 0, 0);
                acc[mt][nt] = __builtin_amdgcn_mfma_f32_16x16x32_bf16(
                        fah[mt], fbl, acc[mt][nt], 0, 0, 0);
                acc[mt][nt] = __builtin_amdgcn_mfma_f32_16x16x32_bf16(
                        fal[mt], fbh, acc[mt][nt], 0, 0, 0);
            }
        }
    }
    // ---- epilogue: quant store + row/col sum & min partials ----------------
    float csum[4] = {0.f, 0.f, 0.f, 0.f};
    unsigned cmin[4] = {0xFFFFFFFFu, 0xFFFFFFFFu, 0xFFFFFFFFu, 0xFFFFFFFFu};
#pragma unroll
    for (int mt = 0; mt < 4; ++mt) {
#pragma unroll
        for (int r = 0; r < 4; ++r) {
            int irow = wi * 64 + mt * 16 + quad * 4 + r;   // local row 0..127
            float rs = 0.0f; unsigned rm = 0xFFFFFFFFu;
            unsigned short qv[4];
#pragma unroll
            for (int nt = 0; nt < 4; ++nt) {
                int jl = wj * 64 + li * 4 + nt;            // local col 0..127
                float dot = acc[mt][nt][r];
                float cost = fminf(fmaxf(1.0f - dot, 0.0f), 2.0f);
                unsigned q = __float2uint_rn(cost * QSCALE);
                qv[nt] = (unsigned short)q;
                rs += dot;
                rm = min(rm, (q << 16) | (unsigned)(j0 + jl));
                csum[nt] += dot;
                cmin[nt] = min(cmin[nt], (q << 16) | (unsigned)(i0 + irow));
            }
            *(ushort4*)&C16[((size_t)b * PP + i0 + irow) * PP + j0 + wj * 64 + li * 4] =
                make_ushort4(qv[0], qv[1], qv[2], qv[3]);
#pragma unroll
            for (int m = 1; m < 16; m <<= 1) {
                rs += __shfl_xor(rs, m, 64);
                rm = min(rm, (unsigned)__shfl_xor((int)rm, m, 64));
            }
            if (li == 0) { rsum2[wj * 128 + irow] = rs; rmin2[wj * 128 + irow] = rm; }
        }
    }
#pragma unroll
    for (int nt = 0; nt < 4; ++nt) {
        float cv = csum[nt]; unsigned cmv = cmin[nt];
#pragma unroll
        for (int m = 16; m < 64; m <<= 1) {
            cv += __shfl_xor(cv, m, 64);
            cmv = min(cmv, (unsigned)__shfl_xor((int)cmv, m, 64));
        }
        if (quad == 0) {
            int jl = wj * 64 + li * 4 + nt;
            csum2[wi * 128 + jl] = cv; cmin2[wi * 128 + jl] = cmv;
        }
    }
    __syncthreads();
    if (t < 128) {
        rpart[(size_t)blockIdx.x * (NB * PP) + b * PP + i0 + t] = rsum2[t] + rsum2[128 + t];
        rminp[(size_t)blockIdx.x * (NB * PP) + b * PP + i0 + t] = min(rmin2[t], rmin2[128 + t]);
        cpart[(size_t)blockIdx.y * (NB * PP) + b * PP + j0 + t] = csum2[t] + csum2[128 + t];
        cminp[(size_t)blockIdx.y * (NB * PP) + b * PP + j0 + t] = min(cmin2[t], cmin2[128 + t]);
    }
}

// ---- combine partials (wide grid: 64 blocks) -------------------------------
__global__ void combine_kernel(const float* __restrict__ rpart, const float* __restrict__ cpart,
                               const unsigned* __restrict__ rminp, const unsigned* __restrict__ cminp,
                               float* __restrict__ rowS, float* __restrict__ colS,
                               unsigned* __restrict__ rowminp, unsigned* __restrict__ colminp) {
    int idx = blockIdx.x * 256 + threadIdx.x;
    float rs = 0.0f, csf = 0.0f;
    unsigned rm = 0xFFFFFFFFu, cm = 0xFFFFFFFFu;
#pragma unroll
    for (int k = 0; k < 16; ++k) {
        rs  += rpart[(size_t)k * (NB * PP) + idx];
        csf += cpart[(size_t)k * (NB * PP) + idx];
        rm = min(rm, rminp[(size_t)k * (NB * PP) + idx]);
        cm = min(cm, cminp[(size_t)k * (NB * PP) + idx]);
    }
    rowS[idx] = rs; colS[idx] = csf;
    rowminp[idx] = rm; colminp[idx] = cm;
}

// ---- weights + thresholds --------------------------------------------------
__device__ __forceinline__ float blockReduceSum256(float v, float* sh) {
    v = waveAllSum(v);
    int lane = threadIdx.x & 63, w = threadIdx.x >> 6;
    if (lane == 0) sh[w] = v;
    __syncthreads();
    float r = sh[0] + sh[1] + sh[2] + sh[3];
    __syncthreads();
    return r;
}

__global__ void weights_kernel(const float* __restrict__ rowS, const float* __restrict__ colS,
                               const unsigned* __restrict__ rowminp, const unsigned* __restrict__ colminp,
                               float* __restrict__ elm, float* __restrict__ eln,
                               float* __restrict__ rowminf, float* __restrict__ colminf,
                               float* __restrict__ cthresh) {
    __shared__ float sh[4];
    int b = blockIdx.x & 7;
    bool isB = blockIdx.x >= 8;
    const float* src = (isB ? colS : rowS) + b * PP;
    float* dst = (isB ? eln : elm) + b * PP;
    int tid = threadIdx.x;
    float x[8];
    float sabs = 0.0f;
#pragma unroll
    for (int q = 0; q < 8; ++q) {
        x[q] = src[tid + q * 256] * (1.0f / (float)PP);
        sabs += fabsf(x[q]);
    }
    sabs = blockReduceSum256(sabs, sh);
    float inv1 = 1.0f / fmaxf(sabs, 1e-12f);
    float spos = 0.0f;
#pragma unroll
    for (int q = 0; q < 8; ++q) {
        x[q] = fmaxf(x[q] * inv1, 0.0f);
        spos += x[q];
    }
    spos = blockReduceSum256(spos, sh);
    float inv2 = 1.0f / fmaxf(spos, 1e-12f);
#pragma unroll
    for (int q = 0; q < 8; ++q)
        dst[tid + q * 256] = EPSF * logf(x[q] * inv2 + 1e-8f);
    if (isB) {
#pragma unroll
        for (int q = 0; q < 8; ++q) {
            int idx = b * PP + tid + q * 256;
            unsigned pc = colminp[idx];
            unsigned arg = pc & 0xffffu;
            unsigned pr = rowminp[b * PP + arg];
            float cmf = (float)(pc >> 16) * S_DEQ;
            colminf[idx] = cmf;
            cthresh[idx] = cmf - (float)(pr >> 16) * S_DEQ + TSEL;
        }
    } else {
#pragma unroll
        for (int q = 0; q < 8; ++q) {
            int idx = b * PP + tid + q * 256;
            rowminf[idx] = (float)(rowminp[idx] >> 16) * S_DEQ;
        }
    }
}

// ---- fused candidate selection: blocks [0,4096) rows, [4096,5120) col qtrs -
__global__ __launch_bounds__(256) void select_kernel(const unsigned short* __restrict__ C16,
        const float* __restrict__ colminf, const float* __restrict__ rowminf,
        const float* __restrict__ cthresh,
        unsigned* __restrict__ rlist, int* __restrict__ rcnt,
        unsigned* __restrict__ clist, int* __restrict__ scnt) {
    __shared__ unsigned tile32[64][36];
    __shared__ float rm_s[64];
    __shared__ unsigned lcnt[64];
    if (blockIdx.x < 4096) {
        // ---- row path: wave per row, ballot compaction (r14-proven) --------
        int w = threadIdx.x >> 6, lane = threadIdx.x & 63;
        int row = blockIdx.x * 4 + w;
        int b = row >> 11;
        const uint4* cp = (const uint4*)(C16 + (size_t)row * PP);
        uint4 q4[4];
#pragma unroll
        for (int g = 0; g < 4; ++g) q4[g] = cp[g * 64 + lane];
        const float* cmb = colminf + b * PP;
        float rpmin = 1e30f;
#pragma unroll
        for (int g = 0; g < 4; ++g) {
            int jb = g * 512 + lane * 8;
            float4 cm0 = *(const float4*)(cmb + jb);
            float4 cm1 = *(const float4*)(cmb + jb + 4);
            float cm[8] = {cm0.x, cm0.y, cm0.z, cm0.w, cm1.x, cm1.y, cm1.z, cm1.w};
            unsigned qq[4] = {q4[g].x, q4[g].y, q4[g].z, q4[g].w};
#pragma unroll
            for (int h = 0; h < 4; ++h) {
                float c0 = (float)(qq[h] & 0xffffu) * S_DEQ;
                float c1 = (float)(qq[h] >> 16) * S_DEQ;
                rpmin = fminf(rpmin, fminf(c0 - cm[h * 2], c1 - cm[h * 2 + 1]));
            }
        }
        float rth = waveAllMin(rpmin) + TSEL;
        int base = 0;
#pragma unroll
        for (int g = 0; g < 4; ++g) {
            int jb = g * 512 + lane * 8;
            float4 cm0 = *(const float4*)(cmb + jb);
            float4 cm1 = *(const float4*)(cmb + jb + 4);
            float cm[8] = {cm0.x, cm0.y, cm0.z, cm0.w, cm1.x, cm1.y, cm1.z, cm1.w};
            unsigned qq[4] = {q4[g].x, q4[g].y, q4[g].z, q4[g].w};
#pragma unroll
            for (int e = 0; e < 8; ++e) {
                unsigned q = (qq[e >> 1] >> ((e & 1) * 16)) & 0xffffu;
                float cf = (float)q * S_DEQ;
                bool rq = (cf - cm[e]) <= rth;
                unsigned long long mb = __ballot(rq);
                if (rq) {
                    int pos = base + __popcll(mb & ((1ull << lane) - 1ull));
                    if (pos < KR) rlist[(size_t)row * KR + pos] = ((unsigned)(jb + e) << 16) | q;
                }
                base += __popcll(mb);
            }
        }
        if (lane == 0) rcnt[row] = base;
    } else {
        // ---- col path: (b, slab, quarter) block; 8 chunks, LDS transpose ---
        int bid = blockIdx.x - 4096;         // 0..1023
        int b = bid >> 7;
        int rem = bid & 127;
        int j0 = (rem >> 2) * 64;
        int r0 = (rem & 3) * 512;
        int qq = rem & 3;
        int t = threadIdx.x;
        int col = t & 63, seg = t >> 6;
        float ctj = cthresh[b * PP + j0 + col];
        unsigned* mylist = clist + ((size_t)(b * PP + j0 + col)) * KC + qq * 128;
        if (t < 64) lcnt[t] = 0;
        int lrow = t >> 3, lcc = t & 7;
        uint4 pf0, pf1; float pfr = 0.0f;
        {
            const unsigned short* base0 = C16 + ((size_t)b * PP + r0 + lrow) * PP + j0;
            pf0 = ((const uint4*)base0)[lcc];
            pf1 = ((const uint4*)(base0 + (size_t)32 * PP))[lcc];
            if (t < 64) pfr = rowminf[b * PP + r0 + t];
        }
        for (int chunk = 0; chunk < 8; ++chunk) {
            *(uint4*)&tile32[lrow][lcc * 4]      = pf0;
            *(uint4*)&tile32[32 + lrow][lcc * 4] = pf1;
            if (t < 64) rm_s[t] = pfr;
            __syncthreads();
            if (chunk < 7) {
                int rn = r0 + (chunk + 1) * 64;
                const unsigned short* base0 = C16 + ((size_t)b * PP + rn + lrow) * PP + j0;
                pf0 = ((const uint4*)base0)[lcc];
                pf1 = ((const uint4*)(base0 + (size_t)32 * PP))[lcc];
                if (t < 64) pfr = rowminf[b * PP + rn + t];
            }
            int rbase = r0 + chunk * 64;
#pragma unroll
            for (int rr = 0; rr < 16; ++rr) {
                int row = seg * 16 + rr;
                unsigned w32 = tile32[row][col >> 1];
                unsigned q = (col & 1) ? (w32 >> 16) : (w32 & 0xffffu);
                float cf = (float)q * S_DEQ;
                if (cf - rm_s[row] <= ctj) {
                    unsigned pos = atomicAdd(&lcnt[col], 1u);
                    if (pos < 128) mylist[pos] = ((unsigned)(rbase + row) << 16) | q;
                }
            }
            __syncthreads();
        }
        if (t < 64)
            scnt[(b * PP + j0 + t) * 4 + qq] = min((int)lcnt[t], 128);
    }
}

// ---- Sinkhorn u-update over row candidates (wave per row) ------------------
__global__ __launch_bounds__(256) void u_kernel(const unsigned* __restrict__ rlist,
        const int* __restrict__ rcnt, const float* __restrict__ v,
        const float* __restrict__ elm, float* __restrict__ u, float* __restrict__ du,
        const int* __restrict__ conv) {
    if (*conv) return;
    int w = threadIdx.x >> 6, lane = threadIdx.x & 63;
    int row = blockIdx.x * 4 + w;
    int b = row >> 11;
    int cnt = min(rcnt[row], KR);
    const unsigned* lst = rlist + (size_t)row * KR;
    const float* vb = v + (b << 11);
    float x[8];
    float m = NEG_INF;
#pragma unroll
    for (int s = 0; s < 8; ++s) {
        int e = lane + s * 64;
        x[s] = NEG_INF;
        if (e < cnt) {
            unsigned wd = lst[e];
            x[s] = vb[wd >> 16] - (float)(wd & 0xffffu) * S_DEQ;
        }
        m = fmaxf(m, x[s]);
    }
    m = waveAllMax(m);
    float s = 0.0f;
#pragma unroll
    for (int k = 0; k < 8; ++k) s += __expf((x[k] - m) * RCPE);
    s = waveAllSum(s);
    if (lane == 0) {
        float un = elm[row] - m - EPSF * logf(s);
        du[row] = fabsf(un - u[row]);
        u[row] = un;
    }
}

// ---- Sinkhorn v-update over col candidates (+ err/conv in block 0) ---------
__global__ __launch_bounds__(256) void v_kernel(const unsigned* __restrict__ clist,
        const int* __restrict__ scnt, const float* __restrict__ u,
        const float* __restrict__ eln, float* __restrict__ v,
        const float* __restrict__ du, int* __restrict__ conv) {
    if (*conv) return;
    int w = threadIdx.x >> 6, lane = threadIdx.x & 63;
    int jg = blockIdx.x * 4 + w;
    int b = jg >> 11;
    int4 sc = *(const int4*)&scnt[jg * 4];
    int cn[4] = {sc.x, sc.y, sc.z, sc.w};
    const unsigned* lst = clist + (size_t)jg * KC;
    const float* ub = u + (b << 11);
    float x[8];
    float m = NEG_INF;
#pragma unroll
    for (int s = 0; s < 8; ++s) {
        int e = lane + s * 64;
        int sg = e >> 7, k = e & 127;
        x[s] = NEG_INF;
        if (k < cn[sg]) {
            unsigned wd = lst[sg * 128 + k];
            x[s] = ub[wd >> 16] - (float)(wd & 0xffffu) * S_DEQ;
        }
        m = fmaxf(m, x[s]);
    }
    m = waveAllMax(m);
    float s = 0.0f;
#pragma unroll
    for (int k = 0; k < 8; ++k) s += __expf((x[k] - m) * RCPE);
    s = waveAllSum(s);
    if (lane == 0)
        v[jg] = eln[jg] - m - EPSF * logf(s);
    if (blockIdx.x == 0) {
        __shared__ float sh[4];
        int t = threadIdx.x;
        float sacc = 0.0f;
#pragma unroll
        for (int q = 0; q < 64; ++q) sacc += du[t + q * 256];
        sacc = waveAllSum(sacc);
        if (lane == 0) sh[w] = sacc;
        __syncthreads();
        if (t == 0) {
            float tot = sh[0] + sh[1] + sh[2] + sh[3];
            if (tot * (1.0f / (float)NB) < THRESHF) *conv = 1;
        }
    }
}

// ---- final: D[b] = sum over row candidates of exp((u+v-C)/eps)*C -----------
__global__ __launch_bounds__(256) void emd_kernel(const unsigned* __restrict__ rlist,
        const int* __restrict__ rcnt, const float* __restrict__ u,
        const float* __restrict__ v, float* __restrict__ out) {
    __shared__ float sh[4];
    int w = threadIdx.x >> 6, lane = threadIdx.x & 63;
    int row = blockIdx.x * 4 + w;
    int b = row >> 11;
    int cnt = min(rcnt[row], KR);
    const unsigned* lst = rlist + (size_t)row * KR;
    const float* vb = v + (b << 11);
    float ui = u[row];
    float s = 0.0f;
#pragma unroll
    for (int k = 0; k < 8; ++k) {
        int e = lane + k * 64;
        if (e < cnt) {
            unsigned wd = lst[e];
            float cf = (float)(wd & 0xffffu) * S_DEQ;
            s += __expf((ui + vb[wd >> 16] - cf) * RCPE) * cf;
        }
    }
    s = waveAllSum(s);
    if (lane == 0) sh[w] = s;
    __syncthreads();
    if (threadIdx.x == 0) atomicAdd(&out[b], sh[0] + sh[1] + sh[2] + sh[3]);
}

extern "C" void kernel_launch(void* const* d_in, const int* in_sizes, int n_in,
                              void* d_out, int out_size, void* d_ws, size_t ws_size,
                              hipStream_t stream) {
    const float* a = (const float*)d_in[0];
    const float* b = (const float*)d_in[1];
    float* out = (float*)d_out;

    const size_t MBs = 1024ull * 1024ull;
    char* ws = (char*)d_ws;
    unsigned short* C16 = (unsigned short*)ws;              // 64 MB
    short* ahi   = (short*)(ws + 64 * MBs);                 // 2 MB each
    short* alo   = (short*)(ws + 66 * MBs);
    short* bhi   = (short*)(ws + 68 * MBs);
    short* blo   = (short*)(ws + 70 * MBs);
    float* rpart = (float*)(ws + 72 * MBs);
    float* cpart = (float*)(ws + 73 * MBs);
    unsigned* rminp = (unsigned*)(ws + 74 * MBs);
    unsigned* cminp = (unsigned*)(ws + 75 * MBs);
    unsigned* rlist = (unsigned*)(ws + 64 * MBs);           // 32 MB, alias
    unsigned* clist = (unsigned*)(ws + 96 * MBs);           // 32 MB
    char* tail = ws + 128 * MBs;
    size_t off = 0;
    const size_t szV = (size_t)NB * PP * 4;                 // 64 KB
    int*   scnt    = (int*)(tail + off); off += (size_t)NB * PP * 4 * 4;
    float* rowS    = (float*)(tail + off); off += szV;
    float* colS    = (float*)(tail + off); off += szV;
    unsigned* rowminp = (unsigned*)(tail + off); off += szV;
    unsigned* colminp = (unsigned*)(tail + off); off += szV;
    float* rowminf = (float*)(tail + off); off += szV;
    float* colminf = (float*)(tail + off); off += szV;
    float* cthresh = (float*)(tail + off); off += szV;
    float* elm     = (float*)(tail + off); off += szV;
    float* eln     = (float*)(tail + off); off += szV;
    float* u       = (float*)(tail + off); off += szV;
    float* v       = (float*)(tail + off); off += szV;
    float* du      = (float*)(tail + off); off += szV;
    int*   rcnt    = (int*)(tail + off); off += szV;
    int*   conv    = (int*)(tail + off); off += 64;
    if (ws_size < 128 * MBs + off) return;

    norm_kernel<<<(2 * NB * PP) / 4, 256, 0, stream>>>(a, b, ahi, alo, bhi, blo,
            u, v, conv, out);
    cost_kernel<<<dim3(PP / 128, PP / 128, NB), 256, 0, stream>>>(
            ahi, alo, bhi, blo, C16, rpart, cpart, rminp, cminp);
    combine_kernel<<<64, 256, 0, stream>>>(rpart, cpart, rminp, cminp,
            rowS, colS, rowminp, colminp);
    weights_kernel<<<16, 256, 0, stream>>>(rowS, colS, rowminp, colminp,
            elm, eln, rowminf, colminf, cthresh);
    select_kernel<<<4096 + 1024, 256, 0, stream>>>(C16, colminf, rowminf,
            cthresh, rlist, rcnt, clist, scnt);
    for (int it = 0; it < TMAX; ++it) {
        u_kernel<<<NB * PP / 4, 256, 0, stream>>>(rlist, rcnt, v, elm, u, du, conv);
        v_kernel<<<NB * PP / 4, 256, 0, stream>>>(clist, scnt, u, eln, v, du, conv);
    }
    emd_kernel<<<NB * PP / 4, 256, 0, stream>>>(rlist, rcnt, u, v, out);
}

// Round 17
// 348.864 us; speedup vs baseline: 1.4468x; 1.1371x over previous
//
#include <hip/hip_runtime.h>
#include <math.h>

#define NB 8
#define PP 2048
#define DD 64
#define EPSF 1e-3f
#define RCPE 1000.0f
#define TMAX 10
#define THRESHF 0.1f
#define NEG_INF (-1e30f)
#define QSCALE 32767.5f                 // cost in [0,2] -> u16
#define S_DEQ  (1.0f / 32767.5f)
#define KR 512                          // row candidate cap
#define KC 512                          // col candidate cap (4 segs x 128)
#define TSEL 0.15f                      // selection margin (PROVEN: 0.12 fails, r6)
// NOTE (r8): cooperative grid.sync costs ~115 us/sync on gfx950. Do not retry.
// NOTE (r12): folding combine into 16-block weights => latency collapse.
// NOTE (r15): col select with 2B/lane strided loads => 2x regression.
// NOTE (r17): emd atomicAdd x4096 to ONE cacheline (out[0..7]) = 55us of
//             serialized RMW. Partials + 8-block finalize instead.

typedef __attribute__((ext_vector_type(8))) short bf16x8;
typedef __attribute__((ext_vector_type(4))) float f32x4;

__device__ __forceinline__ float waveAllMax(float v) {
#pragma unroll
    for (int m = 1; m < 64; m <<= 1) v = fmaxf(v, __shfl_xor(v, m, 64));
    return v;
}
__device__ __forceinline__ float waveAllMin(float v) {
#pragma unroll
    for (int m = 1; m < 64; m <<= 1) v = fminf(v, __shfl_xor(v, m, 64));
    return v;
}
__device__ __forceinline__ float waveAllSum(float v) {
#pragma unroll
    for (int m = 1; m < 64; m <<= 1) v += __shfl_xor(v, m, 64);
    return v;
}
__device__ __forceinline__ short f2bf(float x) {   // round-to-nearest-even bf16
    unsigned b = __float_as_uint(x);
    return (short)((b + 0x7FFFu + ((b >> 16) & 1u)) >> 16);
}
__device__ __forceinline__ float bf2f(short h) {
    return __uint_as_float(((unsigned)(unsigned short)h) << 16);
}

// ---- L2 normalize + bf16 hi/lo split (+ init of u/v/conv/out) --------------
__global__ void norm_kernel(const float* __restrict__ a, const float* __restrict__ b,
                            short* __restrict__ ahi, short* __restrict__ alo,
                            short* __restrict__ bhi, short* __restrict__ blo,
                            float* __restrict__ u, float* __restrict__ v,
                            int* __restrict__ conv, float* __restrict__ out) {
    int gt = blockIdx.x * 256 + threadIdx.x;
    if (gt < NB * PP) { u[gt] = 0.0f; v[gt] = 0.0f; }
    if (gt == 0) *conv = 0;
    if (gt < NB) out[gt] = 0.0f;
    int wave = gt >> 6;
    int lane = threadIdx.x & 63;
    const float* src; short* dhi; short* dlo; int row;
    if (wave < NB * PP) { src = a; dhi = ahi; dlo = alo; row = wave; }
    else                { src = b; dhi = bhi; dlo = blo; row = wave - NB * PP; }
    float x = src[(size_t)row * DD + lane];
    float ss = waveAllSum(x * x);
    float r = 1.0f / fmaxf(sqrtf(ss), 1e-12f);
    float xn = x * r;
    short h = f2bf(xn);
    dhi[(size_t)row * DD + lane] = h;
    dlo[(size_t)row * DD + lane] = f2bf(xn - bf2f(h));
}

// ---- cost GEMM via bf16-split MFMA, pre-split fragments direct from global -
__global__ __launch_bounds__(256) void cost_kernel(const short* __restrict__ ahi,
        const short* __restrict__ alo, const short* __restrict__ bhi,
        const short* __restrict__ blo, unsigned short* __restrict__ C16,
        float* __restrict__ rpart, float* __restrict__ cpart,
        unsigned* __restrict__ rminp, unsigned* __restrict__ cminp) {
    __shared__ float    rsum2[256];
    __shared__ unsigned rmin2[256];
    __shared__ float    csum2[256];
    __shared__ unsigned cmin2[256];
    int b  = blockIdx.z;
    int i0 = blockIdx.y * 128;
    int j0 = blockIdx.x * 128;
    int t = threadIdx.x, w = t >> 6, lane = t & 63;
    int wi = w >> 1, wj = w & 1;
    int quad = lane >> 4, li = lane & 15;
    size_t Aoff = ((size_t)b * PP + i0 + wi * 64) * DD;
    size_t Boff = ((size_t)b * PP + j0 + wj * 64) * DD;
    f32x4 acc[4][4] = {};
#pragma unroll
    for (int kc = 0; kc < 2; ++kc) {
        int k0 = kc * 32 + quad * 8;
        bf16x8 fah[4], fal[4];
#pragma unroll
        for (int mt = 0; mt < 4; ++mt) {
            size_t o = Aoff + (size_t)(mt * 16 + li) * DD + k0;
            fah[mt] = *(const bf16x8*)(ahi + o);
            fal[mt] = *(const bf16x8*)(alo + o);
        }
#pragma unroll
        for (int nt = 0; nt < 4; ++nt) {
            size_t o = Boff + (size_t)(li * 4 + nt) * DD + k0;
            bf16x8 fbh = *(const bf16x8*)(bhi + o);
            bf16x8 fbl = *(const bf16x8*)(blo + o);
#pragma unroll
            for (int mt = 0; mt < 4; ++mt) {
                acc[mt][nt] = __builtin_amdgcn_mfma_f32_16x16x32_bf16(
                        fah[mt], fbh, acc[mt][nt], 0, 0, 0);
                acc[mt][nt] = __builtin_amdgcn_mfma_f32_16x16x32_bf16(
                        fah[mt], fbl, acc[mt][nt], 0, 0, 0);
                acc[mt][nt] = __builtin_amdgcn_mfma_f32_16x16x32_bf16(
                        fal[mt], fbh, acc[mt][nt], 0, 0, 0);
            }
        }
    }
    // ---- epilogue: quant store + row/col sum & min partials ----------------
    float csum[4] = {0.f, 0.f, 0.f, 0.f};
    unsigned cmin[4] = {0xFFFFFFFFu, 0xFFFFFFFFu, 0xFFFFFFFFu, 0xFFFFFFFFu};
#pragma unroll
    for (int mt = 0; mt < 4; ++mt) {
#pragma unroll
        for (int r = 0; r < 4; ++r) {
            int irow = wi * 64 + mt * 16 + quad * 4 + r;   // local row 0..127
            float rs = 0.0f; unsigned rm = 0xFFFFFFFFu;
            unsigned short qv[4];
#pragma unroll
            for (int nt = 0; nt < 4; ++nt) {
                int jl = wj * 64 + li * 4 + nt;            // local col 0..127
                float dot = acc[mt][nt][r];
                float cost = fminf(fmaxf(1.0f - dot, 0.0f), 2.0f);
                unsigned q = __float2uint_rn(cost * QSCALE);
                qv[nt] = (unsigned short)q;
                rs += dot;
                rm = min(rm, (q << 16) | (unsigned)(j0 + jl));
                csum[nt] += dot;
                cmin[nt] = min(cmin[nt], (q << 16) | (unsigned)(i0 + irow));
            }
            *(ushort4*)&C16[((size_t)b * PP + i0 + irow) * PP + j0 + wj * 64 + li * 4] =
                make_ushort4(qv[0], qv[1], qv[2], qv[3]);
#pragma unroll
            for (int m = 1; m < 16; m <<= 1) {
                rs += __shfl_xor(rs, m, 64);
                rm = min(rm, (unsigned)__shfl_xor((int)rm, m, 64));
            }
            if (li == 0) { rsum2[wj * 128 + irow] = rs; rmin2[wj * 128 + irow] = rm; }
        }
    }
#pragma unroll
    for (int nt = 0; nt < 4; ++nt) {
        float cv = csum[nt]; unsigned cmv = cmin[nt];
#pragma unroll
        for (int m = 16; m < 64; m <<= 1) {
            cv += __shfl_xor(cv, m, 64);
            cmv = min(cmv, (unsigned)__shfl_xor((int)cmv, m, 64));
        }
        if (quad == 0) {
            int jl = wj * 64 + li * 4 + nt;
            csum2[wi * 128 + jl] = cv; cmin2[wi * 128 + jl] = cmv;
        }
    }
    __syncthreads();
    if (t < 128) {
        rpart[(size_t)blockIdx.x * (NB * PP) + b * PP + i0 + t] = rsum2[t] + rsum2[128 + t];
        rminp[(size_t)blockIdx.x * (NB * PP) + b * PP + i0 + t] = min(rmin2[t], rmin2[128 + t]);
        cpart[(size_t)blockIdx.y * (NB * PP) + b * PP + j0 + t] = csum2[t] + csum2[128 + t];
        cminp[(size_t)blockIdx.y * (NB * PP) + b * PP + j0 + t] = min(cmin2[t], cmin2[128 + t]);
    }
}

// ---- combine partials (wide grid: 64 blocks) -------------------------------
__global__ void combine_kernel(const float* __restrict__ rpart, const float* __restrict__ cpart,
                               const unsigned* __restrict__ rminp, const unsigned* __restrict__ cminp,
                               float* __restrict__ rowS, float* __restrict__ colS,
                               unsigned* __restrict__ rowminp, unsigned* __restrict__ colminp) {
    int idx = blockIdx.x * 256 + threadIdx.x;
    float rs = 0.0f, csf = 0.0f;
    unsigned rm = 0xFFFFFFFFu, cm = 0xFFFFFFFFu;
#pragma unroll
    for (int k = 0; k < 16; ++k) {
        rs  += rpart[(size_t)k * (NB * PP) + idx];
        csf += cpart[(size_t)k * (NB * PP) + idx];
        rm = min(rm, rminp[(size_t)k * (NB * PP) + idx]);
        cm = min(cm, cminp[(size_t)k * (NB * PP) + idx]);
    }
    rowS[idx] = rs; colS[idx] = csf;
    rowminp[idx] = rm; colminp[idx] = cm;
}

// ---- weights + thresholds --------------------------------------------------
__device__ __forceinline__ float blockReduceSum256(float v, float* sh) {
    v = waveAllSum(v);
    int lane = threadIdx.x & 63, w = threadIdx.x >> 6;
    if (lane == 0) sh[w] = v;
    __syncthreads();
    float r = sh[0] + sh[1] + sh[2] + sh[3];
    __syncthreads();
    return r;
}

__global__ void weights_kernel(const float* __restrict__ rowS, const float* __restrict__ colS,
                               const unsigned* __restrict__ rowminp, const unsigned* __restrict__ colminp,
                               float* __restrict__ elm, float* __restrict__ eln,
                               float* __restrict__ rowminf, float* __restrict__ colminf,
                               float* __restrict__ cthresh) {
    __shared__ float sh[4];
    int b = blockIdx.x & 7;
    bool isB = blockIdx.x >= 8;
    const float* src = (isB ? colS : rowS) + b * PP;
    float* dst = (isB ? eln : elm) + b * PP;
    int tid = threadIdx.x;
    float x[8];
    float sabs = 0.0f;
#pragma unroll
    for (int q = 0; q < 8; ++q) {
        x[q] = src[tid + q * 256] * (1.0f / (float)PP);
        sabs += fabsf(x[q]);
    }
    sabs = blockReduceSum256(sabs, sh);
    float inv1 = 1.0f / fmaxf(sabs, 1e-12f);
    float spos = 0.0f;
#pragma unroll
    for (int q = 0; q < 8; ++q) {
        x[q] = fmaxf(x[q] * inv1, 0.0f);
        spos += x[q];
    }
    spos = blockReduceSum256(spos, sh);
    float inv2 = 1.0f / fmaxf(spos, 1e-12f);
#pragma unroll
    for (int q = 0; q < 8; ++q)
        dst[tid + q * 256] = EPSF * logf(x[q] * inv2 + 1e-8f);
    if (isB) {
#pragma unroll
        for (int q = 0; q < 8; ++q) {
            int idx = b * PP + tid + q * 256;
            unsigned pc = colminp[idx];
            unsigned arg = pc & 0xffffu;
            unsigned pr = rowminp[b * PP + arg];
            float cmf = (float)(pc >> 16) * S_DEQ;
            colminf[idx] = cmf;
            cthresh[idx] = cmf - (float)(pr >> 16) * S_DEQ + TSEL;
        }
    } else {
#pragma unroll
        for (int q = 0; q < 8; ++q) {
            int idx = b * PP + tid + q * 256;
            rowminf[idx] = (float)(rowminp[idx] >> 16) * S_DEQ;
        }
    }
}

// ---- fused candidate selection: blocks [0,4096) rows, [4096,5120) col qtrs -
__global__ __launch_bounds__(256) void select_kernel(const unsigned short* __restrict__ C16,
        const float* __restrict__ colminf, const float* __restrict__ rowminf,
        const float* __restrict__ cthresh,
        unsigned* __restrict__ rlist, int* __restrict__ rcnt,
        unsigned* __restrict__ clist, int* __restrict__ scnt) {
    __shared__ unsigned tile32[64][36];
    __shared__ float rm_s[64];
    __shared__ unsigned lcnt[64];
    if (blockIdx.x < 4096) {
        // ---- row path: wave per row, ballot compaction (r14-proven) --------
        int w = threadIdx.x >> 6, lane = threadIdx.x & 63;
        int row = blockIdx.x * 4 + w;
        int b = row >> 11;
        const uint4* cp = (const uint4*)(C16 + (size_t)row * PP);
        uint4 q4[4];
#pragma unroll
        for (int g = 0; g < 4; ++g) q4[g] = cp[g * 64 + lane];
        const float* cmb = colminf + b * PP;
        float rpmin = 1e30f;
#pragma unroll
        for (int g = 0; g < 4; ++g) {
            int jb = g * 512 + lane * 8;
            float4 cm0 = *(const float4*)(cmb + jb);
            float4 cm1 = *(const float4*)(cmb + jb + 4);
            float cm[8] = {cm0.x, cm0.y, cm0.z, cm0.w, cm1.x, cm1.y, cm1.z, cm1.w};
            unsigned qq[4] = {q4[g].x, q4[g].y, q4[g].z, q4[g].w};
#pragma unroll
            for (int h = 0; h < 4; ++h) {
                float c0 = (float)(qq[h] & 0xffffu) * S_DEQ;
                float c1 = (float)(qq[h] >> 16) * S_DEQ;
                rpmin = fminf(rpmin, fminf(c0 - cm[h * 2], c1 - cm[h * 2 + 1]));
            }
        }
        float rth = waveAllMin(rpmin) + TSEL;
        int base = 0;
#pragma unroll
        for (int g = 0; g < 4; ++g) {
            int jb = g * 512 + lane * 8;
            float4 cm0 = *(const float4*)(cmb + jb);
            float4 cm1 = *(const float4*)(cmb + jb + 4);
            float cm[8] = {cm0.x, cm0.y, cm0.z, cm0.w, cm1.x, cm1.y, cm1.z, cm1.w};
            unsigned qq[4] = {q4[g].x, q4[g].y, q4[g].z, q4[g].w};
#pragma unroll
            for (int e = 0; e < 8; ++e) {
                unsigned q = (qq[e >> 1] >> ((e & 1) * 16)) & 0xffffu;
                float cf = (float)q * S_DEQ;
                bool rq = (cf - cm[e]) <= rth;
                unsigned long long mb = __ballot(rq);
                if (rq) {
                    int pos = base + __popcll(mb & ((1ull << lane) - 1ull));
                    if (pos < KR) rlist[(size_t)row * KR + pos] = ((unsigned)(jb + e) << 16) | q;
                }
                base += __popcll(mb);
            }
        }
        if (lane == 0) rcnt[row] = base;
    } else {
        // ---- col path: (b, slab, quarter) block; 8 chunks, LDS transpose ---
        int bid = blockIdx.x - 4096;         // 0..1023
        int b = bid >> 7;
        int rem = bid & 127;
        int j0 = (rem >> 2) * 64;
        int r0 = (rem & 3) * 512;
        int qq = rem & 3;
        int t = threadIdx.x;
        int col = t & 63, seg = t >> 6;
        float ctj = cthresh[b * PP + j0 + col];
        unsigned* mylist = clist + ((size_t)(b * PP + j0 + col)) * KC + qq * 128;
        if (t < 64) lcnt[t] = 0;
        int lrow = t >> 3, lcc = t & 7;
        uint4 pf0, pf1; float pfr = 0.0f;
        {
            const unsigned short* base0 = C16 + ((size_t)b * PP + r0 + lrow) * PP + j0;
            pf0 = ((const uint4*)base0)[lcc];
            pf1 = ((const uint4*)(base0 + (size_t)32 * PP))[lcc];
            if (t < 64) pfr = rowminf[b * PP + r0 + t];
        }
        for (int chunk = 0; chunk < 8; ++chunk) {
            *(uint4*)&tile32[lrow][lcc * 4]      = pf0;
            *(uint4*)&tile32[32 + lrow][lcc * 4] = pf1;
            if (t < 64) rm_s[t] = pfr;
            __syncthreads();
            if (chunk < 7) {
                int rn = r0 + (chunk + 1) * 64;
                const unsigned short* base0 = C16 + ((size_t)b * PP + rn + lrow) * PP + j0;
                pf0 = ((const uint4*)base0)[lcc];
                pf1 = ((const uint4*)(base0 + (size_t)32 * PP))[lcc];
                if (t < 64) pfr = rowminf[b * PP + rn + t];
            }
            int rbase = r0 + chunk * 64;
#pragma unroll
            for (int rr = 0; rr < 16; ++rr) {
                int row = seg * 16 + rr;
                unsigned w32 = tile32[row][col >> 1];
                unsigned q = (col & 1) ? (w32 >> 16) : (w32 & 0xffffu);
                float cf = (float)q * S_DEQ;
                if (cf - rm_s[row] <= ctj) {
                    unsigned pos = atomicAdd(&lcnt[col], 1u);
                    if (pos < 128) mylist[pos] = ((unsigned)(rbase + row) << 16) | q;
                }
            }
            __syncthreads();
        }
        if (t < 64)
            scnt[(b * PP + j0 + t) * 4 + qq] = min((int)lcnt[t], 128);
    }
}

// ---- Sinkhorn u-update over row candidates (wave per row) ------------------
__global__ __launch_bounds__(256) void u_kernel(const unsigned* __restrict__ rlist,
        const int* __restrict__ rcnt, const float* __restrict__ v,
        const float* __restrict__ elm, float* __restrict__ u, float* __restrict__ du,
        const int* __restrict__ conv) {
    if (*conv) return;
    int w = threadIdx.x >> 6, lane = threadIdx.x & 63;
    int row = blockIdx.x * 4 + w;
    int b = row >> 11;
    int cnt = min(rcnt[row], KR);
    const unsigned* lst = rlist + (size_t)row * KR;
    const float* vb = v + (b << 11);
    float x[8];
    float m = NEG_INF;
#pragma unroll
    for (int s = 0; s < 8; ++s) {
        int e = lane + s * 64;
        x[s] = NEG_INF;
        if (e < cnt) {
            unsigned wd = lst[e];
            x[s] = vb[wd >> 16] - (float)(wd & 0xffffu) * S_DEQ;
        }
        m = fmaxf(m, x[s]);
    }
    m = waveAllMax(m);
    float s = 0.0f;
#pragma unroll
    for (int k = 0; k < 8; ++k) s += __expf((x[k] - m) * RCPE);
    s = waveAllSum(s);
    if (lane == 0) {
        float un = elm[row] - m - EPSF * logf(s);
        du[row] = fabsf(un - u[row]);
        u[row] = un;
    }
}

// ---- Sinkhorn v-update over col candidates (+ err/conv in block 0) ---------
__global__ __launch_bounds__(256) void v_kernel(const unsigned* __restrict__ clist,
        const int* __restrict__ scnt, const float* __restrict__ u,
        const float* __restrict__ eln, float* __restrict__ v,
        const float* __restrict__ du, int* __restrict__ conv) {
    if (*conv) return;
    int w = threadIdx.x >> 6, lane = threadIdx.x & 63;
    int jg = blockIdx.x * 4 + w;
    int b = jg >> 11;
    int4 sc = *(const int4*)&scnt[jg * 4];
    int cn[4] = {sc.x, sc.y, sc.z, sc.w};
    const unsigned* lst = clist + (size_t)jg * KC;
    const float* ub = u + (b << 11);
    float x[8];
    float m = NEG_INF;
#pragma unroll
    for (int s = 0; s < 8; ++s) {
        int e = lane + s * 64;
        int sg = e >> 7, k = e & 127;
        x[s] = NEG_INF;
        if (k < cn[sg]) {
            unsigned wd = lst[sg * 128 + k];
            x[s] = ub[wd >> 16] - (float)(wd & 0xffffu) * S_DEQ;
        }
        m = fmaxf(m, x[s]);
    }
    m = waveAllMax(m);
    float s = 0.0f;
#pragma unroll
    for (int k = 0; k < 8; ++k) s += __expf((x[k] - m) * RCPE);
    s = waveAllSum(s);
    if (lane == 0)
        v[jg] = eln[jg] - m - EPSF * logf(s);
    if (blockIdx.x == 0) {
        __shared__ float sh[4];
        int t = threadIdx.x;
        float sacc = 0.0f;
#pragma unroll
        for (int q = 0; q < 64; ++q) sacc += du[t + q * 256];
        sacc = waveAllSum(sacc);
        if (lane == 0) sh[w] = sacc;
        __syncthreads();
        if (t == 0) {
            float tot = sh[0] + sh[1] + sh[2] + sh[3];
            if (tot * (1.0f / (float)NB) < THRESHF) *conv = 1;
        }
    }
}

// ---- final: block partials (no atomics) + 8-block finalize -----------------
__global__ __launch_bounds__(256) void emd_kernel(const unsigned* __restrict__ rlist,
        const int* __restrict__ rcnt, const float* __restrict__ u,
        const float* __restrict__ v, float* __restrict__ epart) {
    __shared__ float sh[4];
    int w = threadIdx.x >> 6, lane = threadIdx.x & 63;
    int row = blockIdx.x * 4 + w;
    int b = row >> 11;
    int cnt = min(rcnt[row], KR);
    const unsigned* lst = rlist + (size_t)row * KR;
    const float* vb = v + (b << 11);
    float ui = u[row];
    float s = 0.0f;
#pragma unroll
    for (int k = 0; k < 8; ++k) {
        int e = lane + k * 64;
        if (e < cnt) {
            unsigned wd = lst[e];
            float cf = (float)(wd & 0xffffu) * S_DEQ;
            s += __expf((ui + vb[wd >> 16] - cf) * RCPE) * cf;
        }
    }
    s = waveAllSum(s);
    if (lane == 0) sh[w] = s;
    __syncthreads();
    if (threadIdx.x == 0) epart[blockIdx.x] = sh[0] + sh[1] + sh[2] + sh[3];
}

__global__ __launch_bounds__(256) void emd_finalize(const float* __restrict__ epart,
                                                    float* __restrict__ out) {
    __shared__ float sh[4];
    int b = blockIdx.x;
    int t = threadIdx.x;
    float s = epart[b * 512 + t] + epart[b * 512 + 256 + t];
    s = blockReduceSum256(s, sh);
    if (t == 0) out[b] = s;
}

extern "C" void kernel_launch(void* const* d_in, const int* in_sizes, int n_in,
                              void* d_out, int out_size, void* d_ws, size_t ws_size,
                              hipStream_t stream) {
    const float* a = (const float*)d_in[0];
    const float* b = (const float*)d_in[1];
    float* out = (float*)d_out;

    const size_t MBs = 1024ull * 1024ull;
    char* ws = (char*)d_ws;
    unsigned short* C16 = (unsigned short*)ws;              // 64 MB
    short* ahi   = (short*)(ws + 64 * MBs);                 // 2 MB each
    short* alo   = (short*)(ws + 66 * MBs);
    short* bhi   = (short*)(ws + 68 * MBs);
    short* blo   = (short*)(ws + 70 * MBs);
    float* rpart = (float*)(ws + 72 * MBs);
    float* cpart = (float*)(ws + 73 * MBs);
    unsigned* rminp = (unsigned*)(ws + 74 * MBs);
    unsigned* cminp = (unsigned*)(ws + 75 * MBs);
    unsigned* rlist = (unsigned*)(ws + 64 * MBs);           // 32 MB, alias
    unsigned* clist = (unsigned*)(ws + 96 * MBs);           // 32 MB
    char* tail = ws + 128 * MBs;
    size_t off = 0;
    const size_t szV = (size_t)NB * PP * 4;                 // 64 KB
    int*   scnt    = (int*)(tail + off); off += (size_t)NB * PP * 4 * 4;
    float* rowS    = (float*)(tail + off); off += szV;
    float* colS    = (float*)(tail + off); off += szV;
    unsigned* rowminp = (unsigned*)(tail + off); off += szV;
    unsigned* colminp = (unsigned*)(tail + off); off += szV;
    float* rowminf = (float*)(tail + off); off += szV;
    float* colminf = (float*)(tail + off); off += szV;
    float* cthresh = (float*)(tail + off); off += szV;
    float* elm     = (float*)(tail + off); off += szV;
    float* eln     = (float*)(tail + off); off += szV;
    float* u       = (float*)(tail + off); off += szV;
    float* v       = (float*)(tail + off); off += szV;
    float* du      = (float*)(tail + off); off += szV;
    int*   rcnt    = (int*)(tail + off); off += szV;
    int*   conv    = (int*)(tail + off); off += 64;
    float* epart   = rowS;   // 4096 floats; rowS dead after weights_kernel
    if (ws_size < 128 * MBs + off) return;

    norm_kernel<<<(2 * NB * PP) / 4, 256, 0, stream>>>(a, b, ahi, alo, bhi, blo,
            u, v, conv, out);
    cost_kernel<<<dim3(PP / 128, PP / 128, NB), 256, 0, stream>>>(
            ahi, alo, bhi, blo, C16, rpart, cpart, rminp, cminp);
    combine_kernel<<<64, 256, 0, stream>>>(rpart, cpart, rminp, cminp,
            rowS, colS, rowminp, colminp);
    weights_kernel<<<16, 256, 0, stream>>>(rowS, colS, rowminp, colminp,
            elm, eln, rowminf, colminf, cthresh);
    select_kernel<<<4096 + 1024, 256, 0, stream>>>(C16, colminf, rowminf,
            cthresh, rlist, rcnt, clist, scnt);
    for (int it = 0; it < TMAX; ++it) {
        u_kernel<<<NB * PP / 4, 256, 0, stream>>>(rlist, rcnt, v, elm, u, du, conv);
        v_kernel<<<NB * PP / 4, 256, 0, stream>>>(clist, scnt, u, eln, v, du, conv);
    }
    emd_kernel<<<NB * PP / 4, 256, 0, stream>>>(rlist, rcnt, u, v, epart);
    emd_finalize<<<NB, 256, 0, stream>>>(epart, out);
}